// Round 1
// baseline (350.391 us; speedup 1.0000x reference)
//
#include <hip/hip_runtime.h>
#include <math.h>

#define NB 32
#define NC 512
#define NF 1025

// ws layout (floats)
#define WS_MEAN 0
#define WS_SSTD 65536
#define WS_RSTD 131072
#define WS_GACC 196608
#define WS_WGT  229408
#define WS_PART 262208                    // optional: 2 × 65536 × {sum,sq}
#define WS_END_SPLIT (262208 + 262144)
// optional cached spectrum: NB*NC rows × 1024 complex = 33,554,432 floats (134 MB)
#define WS_SPEC WS_END_SPLIT
#define WS_SPEC_FLOATS (NB * NC * 2048)
#define WS_END_CACHE (WS_SPEC + WS_SPEC_FLOATS)

#define PIDX(a) ((a) + ((a) >> 4))

// ---------- Stockham radix-4 stage: 256 threads, 1024 pts, src->dst ----------
// Reads are always at t+256c (stride-1, conflict-free, thread-private slots).
// Writes at q + s*(4p+c); the >>4 skew keeps them ~2-way.
// Twiddle w1 = (w1c, w1s) is precomputed per thread per stage by the caller
// (it only depends on t and ls — hoisted out of the per-FFT loop).
__device__ __forceinline__ void stage4(const float* __restrict__ sr,
                                       const float* __restrict__ si,
                                       float* __restrict__ dr,
                                       float* __restrict__ di,
                                       const int ls, const float w1c, const float w1s,
                                       const bool fwd) {
  const int t = threadIdx.x;
  const int s = 1 << ls;
  const int q = t & (s - 1);
  const int p = t >> ls;
  __syncthreads();
  const float ar = sr[PIDX(t)],       ai = si[PIDX(t)];
  const float br = sr[PIDX(t + 256)], bi = si[PIDX(t + 256)];
  const float cr = sr[PIDX(t + 512)], ci = si[PIDX(t + 512)];
  const float er = sr[PIDX(t + 768)], ei = si[PIDX(t + 768)];
  const float apcr = ar + cr, apci = ai + ci;
  const float amcr = ar - cr, amci = ai - ci;
  const float bpdr = br + er, bpdi = bi + ei;
  const float bmdr = br - er, bmdi = bi - ei;
  const float w2r = w1c * w1c - w1s * w1s, w2i = 2.0f * w1c * w1s;
  const float w3r = w2r * w1c - w2i * w1s, w3i = w2r * w1s + w2i * w1c;
  float u1r, u1i, u3r, u3i;
  if (fwd) {  // X1 = w1*(amc - j*bmd), X3 = w3*(amc + j*bmd)
    u1r = amcr + bmdi; u1i = amci - bmdr;
    u3r = amcr - bmdi; u3i = amci + bmdr;
  } else {    // inverse: conjugated
    u1r = amcr - bmdi; u1i = amci + bmdr;
    u3r = amcr + bmdi; u3i = amci - bmdr;
  }
  const float x0r = apcr + bpdr, x0i = apci + bpdi;
  const float v2r = apcr - bpdr, v2i = apci - bpdi;
  const float x1r = w1c * u1r - w1s * u1i, x1i = w1c * u1i + w1s * u1r;
  const float x2r = w2r * v2r - w2i * v2i, x2i = w2r * v2i + w2i * v2r;
  const float x3r = w3r * u3r - w3i * u3i, x3i = w3r * u3i + w3i * u3r;
  const int base = q + ((p << 2) << ls);
  dr[PIDX(base)] = x0r;             di[PIDX(base)] = x0i;
  dr[PIDX(base + s)] = x1r;         di[PIDX(base + s)] = x1i;
  dr[PIDX(base + 2 * s)] = x2r;     di[PIDX(base + 2 * s)] = x2i;
  dr[PIDX(base + 3 * s)] = x3r;     di[PIDX(base + 3 * s)] = x3i;
}

// Last stage (ls=8): p = t>>8 = 0 for t<256, so w1=w2=w3=(1,0).
// No sincos, no twiddle multiplies. base = t; writes land in the same
// skewed slots the thread later reads in the epilogue.
__device__ __forceinline__ void stage4_nt(const float* __restrict__ sr,
                                          const float* __restrict__ si,
                                          float* __restrict__ dr,
                                          float* __restrict__ di,
                                          const bool fwd) {
  const int t = threadIdx.x;
  __syncthreads();
  const float ar = sr[PIDX(t)],       ai = si[PIDX(t)];
  const float br = sr[PIDX(t + 256)], bi = si[PIDX(t + 256)];
  const float cr = sr[PIDX(t + 512)], ci = si[PIDX(t + 512)];
  const float er = sr[PIDX(t + 768)], ei = si[PIDX(t + 768)];
  const float apcr = ar + cr, apci = ai + ci;
  const float amcr = ar - cr, amci = ai - ci;
  const float bpdr = br + er, bpdi = bi + ei;
  const float bmdr = br - er, bmdi = bi - ei;
  float u1r, u1i, u3r, u3i;
  if (fwd) {
    u1r = amcr + bmdi; u1i = amci - bmdr;
    u3r = amcr - bmdi; u3i = amci + bmdr;
  } else {
    u1r = amcr - bmdi; u1i = amci + bmdr;
    u3r = amcr + bmdi; u3i = amci - bmdr;
  }
  dr[PIDX(t)] = apcr + bpdr;        di[PIDX(t)] = apci + bpdi;
  dr[PIDX(t + 256)] = u1r;          di[PIDX(t + 256)] = u1i;
  dr[PIDX(t + 512)] = apcr - bpdr;  di[PIDX(t + 512)] = apci - bpdi;
  dr[PIDX(t + 768)] = u3r;          di[PIDX(t + 768)] = u3i;
}

// Per-thread per-stage twiddles, computed once per kernel.
// Stage ls: w1 = exp(-2*pi*i * (4^k) * p / 1024) with p = t >> ls.
__device__ __forceinline__ void fft_twiddles(int t, float& c0, float& s0,
                                             float& c1, float& s1,
                                             float& c2, float& s2,
                                             float& c3, float& s3) {
  __sincosf(-0.00613592315f * (float)t, &s0, &c0);
  __sincosf(-0.02454369261f * (float)(t >> 2), &s1, &c1);
  __sincosf(-0.09817477042f * (float)(t >> 4), &s2, &c2);
  __sincosf(-0.39269908170f * (float)(t >> 6), &s3, &c3);
}

// natural in A -> natural out in B
__device__ __forceinline__ void fft_fwd1024(float* Ar, float* Ai, float* Br, float* Bi,
                                            float c0, float s0, float c1, float s1,
                                            float c2, float s2, float c3, float s3) {
  stage4(Ar, Ai, Br, Bi, 0, c0, s0, true);
  stage4(Br, Bi, Ar, Ai, 2, c1, s1, true);
  stage4(Ar, Ai, Br, Bi, 4, c2, s2, true);
  stage4(Br, Bi, Ar, Ai, 6, c3, s3, true);
  stage4_nt(Ar, Ai, Br, Bi, true);
}
// natural in B -> natural out in A (unnormalized inverse); twiddles conjugated
__device__ __forceinline__ void fft_inv1024(float* Ar, float* Ai, float* Br, float* Bi,
                                            float c0, float s0, float c1, float s1,
                                            float c2, float s2, float c3, float s3) {
  stage4(Br, Bi, Ar, Ai, 0, c0, -s0, false);
  stage4(Ar, Ai, Br, Bi, 2, c1, -s1, false);
  stage4(Br, Bi, Ar, Ai, 4, c2, -s2, false);
  stage4(Ar, Ai, Br, Bi, 6, c3, -s3, false);
  stage4_nt(Br, Bi, Ar, Ai, false);
}

// ---------------- moments: single-pass fallback ----------------
__global__ __launch_bounds__(256) void kmoments(const float* __restrict__ x,
                                                float* __restrict__ ws) {
  const int b = blockIdx.x >> 3;
  const int l = ((blockIdx.x & 7) << 8) + threadIdx.x;
  const float* px = x + (size_t)b * (NC * 2048) + l;
  float sum = 0.f, sq = 0.f;
#pragma unroll 16
  for (int c = 0; c < NC; ++c) {
    float v = px[(size_t)c * 2048];
    sum += v;
    sq = fmaf(v, v, sq);
  }
  float mean = sum * (1.0f / 512.0f);
  float var = fmaf(-512.0f * mean, mean, sq) * (1.0f / 511.0f) + 1e-5f;
  float ss = sqrtf(var);
  int o = (b << 11) + l;
  ws[WS_MEAN + o] = mean;
  ws[WS_SSTD + o] = ss;
  ws[WS_RSTD + o] = 1.0f / ss;
}

// ---------------- moments: 2-way channel split ----------------
__global__ __launch_bounds__(256) void kmoments_part(const float* __restrict__ x,
                                                     float* __restrict__ ws) {
  const int b = blockIdx.x >> 3;
  const int l = ((blockIdx.x & 7) << 8) + threadIdx.x;
  const int half = blockIdx.y;
  const float* px = x + (size_t)b * (NC * 2048) + (size_t)(half * 256) * 2048 + l;
  float sum = 0.f, sq = 0.f;
#pragma unroll 16
  for (int c = 0; c < 256; ++c) {
    float v = px[(size_t)c * 2048];
    sum += v;
    sq = fmaf(v, v, sq);
  }
  int o = (b << 11) + l;
  float2* part = (float2*)(ws + WS_PART) + (half << 16) + o;
  float2 pv; pv.x = sum; pv.y = sq;
  *part = pv;
}

__global__ __launch_bounds__(256) void kmoments_fin(float* __restrict__ ws) {
  const int o = blockIdx.x * 256 + threadIdx.x;
  const float2* part = (const float2*)(ws + WS_PART);
  float2 p0 = part[o];
  float2 p1 = part[(1 << 16) + o];
  float sum = p0.x + p1.x, sq = p0.y + p1.y;
  float mean = sum * (1.0f / 512.0f);
  float var = fmaf(-512.0f * mean, mean, sq) * (1.0f / 511.0f) + 1e-5f;
  float ss = sqrtf(var);
  ws[WS_MEAN + o] = mean;
  ws[WS_SSTD + o] = ss;
  ws[WS_RSTD + o] = 1.0f / ss;
}

// ------- spectrum magnitudes: fwd FFT per row, per-thread register bins -------
// When zout != nullptr, also stores the full 1024-pt complex spectrum per row
// so kapply_z can skip the forward FFT entirely.
__global__ __launch_bounds__(256) void kspec(const float* __restrict__ x,
                                             float* __restrict__ ws,
                                             float2* __restrict__ zout) {
  __shared__ float Ar[1088], Ai[1088], Br[1088], Bi[1088];
  const int tid = threadIdx.x;
  const int b = blockIdx.x >> 6;
  const int c0 = (blockIdx.x & 63) << 3;
  const float2* mean2 = (const float2*)(ws + WS_MEAN) + ((size_t)b << 10);
  const float2* rstd2 = (const float2*)(ws + WS_RSTD) + ((size_t)b << 10);
  float2 mv[4], rv[4];
#pragma unroll
  for (int j = 0; j < 4; ++j) {
    mv[j] = mean2[tid + (j << 8)];
    rv[j] = rstd2[tid + (j << 8)];
  }
  // combine twiddles are fixed per thread: W = e^{-i pi k/1024}, k=tid, tid+256
  float w1s, w1c, w2s, w2c;
  __sincosf(-0.00306796158f * (float)tid, &w1s, &w1c);
  __sincosf(-0.00306796158f * (float)(tid + 256), &w2s, &w2c);
  // per-stage FFT twiddles, hoisted out of the 8-row loop (was 40 sincos, now 4)
  float c0t, s0t, c1t, s1t, c2t, s2t, c3t, s3t;
  fft_twiddles(tid, c0t, s0t, c1t, s1t, c2t, s2t, c3t, s3t);
  float acc0 = 0.f, acc1 = 0.f, acc2 = 0.f, acc3 = 0.f, acc4 = 0.f;
  const float2* xrow = (const float2*)x + ((size_t)(b * NC + c0) << 10);
  float2 v[4];
#pragma unroll
  for (int j = 0; j < 4; ++j) v[j] = xrow[tid + (j << 8)];
  for (int r = 0; r < 8; ++r) {
#pragma unroll
    for (int j = 0; j < 4; ++j) {
      const int n = tid + (j << 8);
      Ar[PIDX(n)] = (v[j].x - mv[j].x) * rv[j].x;
      Ai[PIDX(n)] = (v[j].y - mv[j].y) * rv[j].y;
    }
    if (r < 7) {
      const float2* nx = xrow + ((size_t)(r + 1) << 10);
#pragma unroll
      for (int j = 0; j < 4; ++j) v[j] = nx[tid + (j << 8)];
    }
    fft_fwd1024(Ar, Ai, Br, Bi, c0t, s0t, c1t, s1t, c2t, s2t, c3t, s3t);
    __syncthreads();  // B fully written before cross-thread reads
    if (zout) {       // cache spectrum for kapply_z (uniform branch)
      float2* zrow = zout + ((size_t)(b * NC + c0 + r) << 10);
#pragma unroll
      for (int j = 0; j < 4; ++j) {
        const int n = tid + (j << 8);
        float2 zv; zv.x = Br[PIDX(n)]; zv.y = Bi[PIDX(n)];
        zrow[n] = zv;
      }
    }
    if (tid == 0) {
      float zr = Br[PIDX(0)], zi = Bi[PIDX(0)];
      acc0 += fabsf(zr + zi);         // bin 0
      acc1 += fabsf(zr - zi);         // bin 1024
      float mr = Br[PIDX(512)], mi = Bi[PIDX(512)];
      acc4 += sqrtf(mr * mr + mi * mi);  // bin 512
    } else {
      const int k = tid;
      float zkr = Br[PIDX(k)], zki = Bi[PIDX(k)];
      float zmr = Br[PIDX(1024 - k)], zmi = Bi[PIDX(1024 - k)];
      float Ar_ = 0.5f * (zkr + zmr), Ai_ = 0.5f * (zki - zmi);
      float Br_ = 0.5f * (zki + zmi), Bi_ = -0.5f * (zkr - zmr);
      float WBr = Br_ * w1c - Bi_ * w1s, WBi = Br_ * w1s + Bi_ * w1c;
      float Xr = Ar_ + WBr, Xi = Ai_ + WBi;
      float Yr = Ar_ - WBr, Yi = Ai_ - WBi;
      acc0 += sqrtf(Xr * Xr + Xi * Xi);     // bin k
      acc1 += sqrtf(Yr * Yr + Yi * Yi);     // bin 1024-k
    }
    {
      const int k = tid + 256;
      float zkr = Br[PIDX(k)], zki = Bi[PIDX(k)];
      float zmr = Br[PIDX(1024 - k)], zmi = Bi[PIDX(1024 - k)];
      float Ar_ = 0.5f * (zkr + zmr), Ai_ = 0.5f * (zki - zmi);
      float Br_ = 0.5f * (zki + zmi), Bi_ = -0.5f * (zkr - zmr);
      float WBr = Br_ * w2c - Bi_ * w2s, WBi = Br_ * w2s + Bi_ * w2c;
      float Xr = Ar_ + WBr, Xi = Ai_ + WBi;
      float Yr = Ar_ - WBr, Yi = Ai_ - WBi;
      acc2 += sqrtf(Xr * Xr + Xi * Xi);     // bin k
      acc3 += sqrtf(Yr * Yr + Yi * Yi);     // bin 1024-k
    }
  }
  float* g = ws + WS_GACC + b * NF;
  atomicAdd(g + tid, acc0);
  atomicAdd(g + 1024 - tid, acc1);
  atomicAdd(g + tid + 256, acc2);
  atomicAdd(g + 768 - tid, acc3);
  if (tid == 0) atomicAdd(g + 512, acc4);
}

// ---------------- gating softmax + band weights ----------------
__global__ __launch_bounds__(256) void kgate(float* __restrict__ ws,
                                             const float* __restrict__ gw,
                                             const float* __restrict__ gb,
                                             const float* __restrict__ bb) {
  const float* gacc = ws + WS_GACC;
  float* wgt = ws + WS_WGT;
  const int b = blockIdx.x;
  const int tid = threadIdx.x;
  __shared__ float red[256];
  __shared__ float sc[8];
  __shared__ int sidx[9];
  float acc[8];
#pragma unroll
  for (int e = 0; e < 8; ++e) acc[e] = 0.f;
  for (int f = tid; f < NF; f += 256) {
    float g = gacc[b * NF + f] * (1.0f / 512.0f);
#pragma unroll
    for (int e = 0; e < 8; ++e) acc[e] = fmaf(g, gw[e * NF + f], acc[e]);
  }
#pragma unroll
  for (int e = 0; e < 8; ++e) {
    __syncthreads();
    red[tid] = acc[e];
    __syncthreads();
    for (int s2 = 128; s2 > 0; s2 >>= 1) {
      if (tid < s2) red[tid] += red[tid + s2];
      __syncthreads();
    }
    if (tid == 0) sc[e] = red[0] + gb[e];
  }
  __syncthreads();
  if (tid == 0) {
    float mx = sc[0];
    for (int e = 1; e < 8; ++e) mx = fmaxf(mx, sc[e]);
    float sum = 0.f;
    float ex[8];
    for (int e = 0; e < 8; ++e) { ex[e] = expf(sc[e] - mx); sum += ex[e]; }
    for (int e = 0; e < 8; ++e) sc[e] = ex[e] / sum;
    float sv[7];
    for (int i2 = 0; i2 < 7; ++i2) sv[i2] = 1.0f / (1.0f + expf(-bb[i2]));
    for (int i2 = 1; i2 < 7; ++i2) {
      float key = sv[i2];
      int j2 = i2 - 1;
      while (j2 >= 0 && sv[j2] > key) { sv[j2 + 1] = sv[j2]; --j2; }
      sv[j2 + 1] = key;
    }
    sidx[0] = 0;
    for (int i2 = 0; i2 < 7; ++i2) sidx[i2 + 1] = (int)(sv[i2] * 1025.0f);
    sidx[8] = 1025;
  }
  __syncthreads();
  for (int f = tid; f < NF; f += 256) {
    float wv = 0.f;
#pragma unroll
    for (int e = 0; e < 8; ++e)
      if (f >= sidx[e] && f < sidx[e + 1]) wv += sc[e];
    wgt[b * NF + f] = wv;
  }
}

// pair combine with spectral weights, in-place on (k, 1024-k)
__device__ __forceinline__ void combine_pair(float* __restrict__ zr_, float* __restrict__ zi_,
                                             int k, float wc, float ws_, float wk, float wmk) {
  const int ik = PIDX(k), im = PIDX(1024 - k);
  float zkr = zr_[ik], zki = zi_[ik];
  float zmr = zr_[im], zmi = zi_[im];
  float Ar_ = 0.5f * (zkr + zmr), Ai_ = 0.5f * (zki - zmi);
  float Br2 = 0.5f * (zki + zmi), Bi2 = -0.5f * (zkr - zmr);
  float WBr = Br2 * wc - Bi2 * ws_, WBi = Br2 * ws_ + Bi2 * wc;
  float Xr = Ar_ + WBr, Xi = Ai_ + WBi;    // X[k]
  float Xcr = Ar_ - WBr, Xci = Ai_ - WBi;  // conj(X[1024-k])
  float XpR = wk * Xr, XpI = wk * Xi;
  float XcpR = wmk * Xcr, XcpI = wmk * Xci;
  float Apr = 0.5f * (XpR + XcpR), Api = 0.5f * (XpI + XcpI);
  float Er = 0.5f * (XpR - XcpR), Ei = 0.5f * (XpI - XcpI);
  float Bpr = Er * wc + Ei * ws_;   // conj(W)*E
  float Bpi = Ei * wc - Er * ws_;
  zr_[ik] = Apr - Bpi;  zi_[ik] = Api + Bpr;
  zr_[im] = Apr + Bpi;  zi_[im] = Bpr - Api;
}

// ------- apply (fallback): fwd FFT, weight, inv FFT, de-normalize, store -------
__global__ __launch_bounds__(256) void kapply(const float* __restrict__ x,
                                              float* __restrict__ out,
                                              const float* __restrict__ ws) {
  __shared__ float Ar[1088], Ai[1088], Br[1088], Bi[1088];
  const int tid = threadIdx.x;
  const int b = blockIdx.x >> 9;
  const float2* mean2 = (const float2*)(ws + WS_MEAN) + ((size_t)b << 10);
  const float2* sstd2 = (const float2*)(ws + WS_SSTD) + ((size_t)b << 10);
  const float2* rstd2 = (const float2*)(ws + WS_RSTD) + ((size_t)b << 10);
  const float2* x2 = (const float2*)x + ((size_t)blockIdx.x << 10);
  const float* wrow = ws + WS_WGT + b * NF;
  float wk1 = wrow[tid];
  float wm1 = wrow[1024 - tid];
  float wk2 = wrow[tid + 256];
  float wm2 = wrow[768 - tid];
  float wmid = wrow[512];
  float w1s, w1c, w2s, w2c;
  __sincosf(-0.00306796158f * (float)tid, &w1s, &w1c);
  __sincosf(-0.00306796158f * (float)(tid + 256), &w2s, &w2c);
  float c0t, s0t, c1t, s1t, c2t, s2t, c3t, s3t;
  fft_twiddles(tid, c0t, s0t, c1t, s1t, c2t, s2t, c3t, s3t);
  float2 mv[4], rv[4];
#pragma unroll
  for (int j = 0; j < 4; ++j) {
    mv[j] = mean2[tid + (j << 8)];
    rv[j] = rstd2[tid + (j << 8)];
  }
#pragma unroll
  for (int j = 0; j < 4; ++j) {
    const int n = tid + (j << 8);
    float2 v = x2[n];
    Ar[PIDX(n)] = (v.x - mv[j].x) * rv[j].x;
    Ai[PIDX(n)] = (v.y - mv[j].y) * rv[j].y;
  }
  fft_fwd1024(Ar, Ai, Br, Bi, c0t, s0t, c1t, s1t, c2t, s2t, c3t, s3t);
  __syncthreads();  // B complete before cross-thread pair access
  if (tid == 0) {
    float zr = Br[PIDX(0)], zi = Bi[PIDX(0)];
    float X0 = (zr + zi) * wk1;
    float XM = (zr - zi) * wm1;
    Br[PIDX(0)] = 0.5f * (X0 + XM);
    Bi[PIDX(0)] = 0.5f * (X0 - XM);
    Br[PIDX(512)] *= wmid;
    Bi[PIDX(512)] *= wmid;
  } else {
    combine_pair(Br, Bi, tid, w1c, w1s, wk1, wm1);
  }
  combine_pair(Br, Bi, tid + 256, w2c, w2s, wk2, wm2);
  fft_inv1024(Ar, Ai, Br, Bi, c0t, s0t, c1t, s1t, c2t, s2t, c3t, s3t);
  // epilogue: thread t reads exactly the slots it wrote in the last stage
  const float inv = 1.0f / 1024.0f;
  float2* out2 = (float2*)out + ((size_t)blockIdx.x << 10);
#pragma unroll
  for (int j = 0; j < 4; ++j) {
    const int n = tid + (j << 8);
    float2 ss = sstd2[n];
    float2 o;
    o.x = fmaf(Ar[PIDX(n)] * inv, ss.x, mv[j].x);
    o.y = fmaf(Ai[PIDX(n)] * inv, ss.y, mv[j].y);
    out2[n] = o;
  }
}

// ------- apply (cached): load Z, weight, inv FFT, de-normalize, store -------
// Skips the forward FFT + normalize + x read entirely: the spectrum was
// already computed (post-normalization) by kspec and cached in ws.
__global__ __launch_bounds__(256) void kapply_z(const float2* __restrict__ z,
                                                float* __restrict__ out,
                                                const float* __restrict__ ws) {
  __shared__ float Ar[1088], Ai[1088], Br[1088], Bi[1088];
  const int tid = threadIdx.x;
  const int b = blockIdx.x >> 9;
  const float2* mean2 = (const float2*)(ws + WS_MEAN) + ((size_t)b << 10);
  const float2* sstd2 = (const float2*)(ws + WS_SSTD) + ((size_t)b << 10);
  const float* wrow = ws + WS_WGT + b * NF;
  float wk1 = wrow[tid];
  float wm1 = wrow[1024 - tid];
  float wk2 = wrow[tid + 256];
  float wm2 = wrow[768 - tid];
  float wmid = wrow[512];
  float w1s, w1c, w2s, w2c;
  __sincosf(-0.00306796158f * (float)tid, &w1s, &w1c);
  __sincosf(-0.00306796158f * (float)(tid + 256), &w2s, &w2c);
  float c0t, s0t, c1t, s1t, c2t, s2t, c3t, s3t;
  fft_twiddles(tid, c0t, s0t, c1t, s1t, c2t, s2t, c3t, s3t);
  const float2* zrow = z + ((size_t)blockIdx.x << 10);
  float2 mv[4], ssv[4];
#pragma unroll
  for (int j = 0; j < 4; ++j) {
    mv[j] = mean2[tid + (j << 8)];
    ssv[j] = sstd2[tid + (j << 8)];
  }
#pragma unroll
  for (int j = 0; j < 4; ++j) {
    const int n = tid + (j << 8);
    float2 v = zrow[n];
    Br[PIDX(n)] = v.x;
    Bi[PIDX(n)] = v.y;
  }
  __syncthreads();  // B complete before cross-thread pair access
  if (tid == 0) {
    float zr = Br[PIDX(0)], zi = Bi[PIDX(0)];
    float X0 = (zr + zi) * wk1;
    float XM = (zr - zi) * wm1;
    Br[PIDX(0)] = 0.5f * (X0 + XM);
    Bi[PIDX(0)] = 0.5f * (X0 - XM);
    Br[PIDX(512)] *= wmid;
    Bi[PIDX(512)] *= wmid;
  } else {
    combine_pair(Br, Bi, tid, w1c, w1s, wk1, wm1);
  }
  combine_pair(Br, Bi, tid + 256, w2c, w2s, wk2, wm2);
  fft_inv1024(Ar, Ai, Br, Bi, c0t, s0t, c1t, s1t, c2t, s2t, c3t, s3t);
  // epilogue: thread t reads exactly the slots it wrote in the last stage
  const float inv = 1.0f / 1024.0f;
  float2* out2 = (float2*)out + ((size_t)blockIdx.x << 10);
#pragma unroll
  for (int j = 0; j < 4; ++j) {
    const int n = tid + (j << 8);
    float2 o;
    o.x = fmaf(Ar[PIDX(n)] * inv, ssv[j].x, mv[j].x);
    o.y = fmaf(Ai[PIDX(n)] * inv, ssv[j].y, mv[j].y);
    out2[n] = o;
  }
}

extern "C" void kernel_launch(void* const* d_in, const int* in_sizes, int n_in,
                              void* d_out, int out_size, void* d_ws, size_t ws_size,
                              hipStream_t stream) {
  const float* x = (const float*)d_in[0];
  const float* bb = (const float*)d_in[1];
  const float* gw = (const float*)d_in[2];
  const float* gb = (const float*)d_in[3];
  float* ws = (float*)d_ws;
  float* out = (float*)d_out;

  const bool split = ws_size >= (size_t)WS_END_SPLIT * sizeof(float);
  const bool cache = ws_size >= (size_t)WS_END_CACHE * sizeof(float);

  hipMemsetAsync((char*)d_ws + WS_GACC * sizeof(float), 0, (NB * NF) * sizeof(float), stream);
  if (split) {
    kmoments_part<<<dim3(NB * 8, 2), dim3(256), 0, stream>>>(x, ws);
    kmoments_fin<<<dim3(256), dim3(256), 0, stream>>>(ws);
  } else {
    kmoments<<<dim3(NB * 8), dim3(256), 0, stream>>>(x, ws);
  }
  kspec<<<dim3(NB * 64), dim3(256), 0, stream>>>(x, ws,
      cache ? (float2*)(ws + WS_SPEC) : nullptr);
  kgate<<<dim3(NB), dim3(256), 0, stream>>>(ws, gw, gb, bb);
  if (cache) {
    kapply_z<<<dim3(NB * NC), dim3(256), 0, stream>>>((const float2*)(ws + WS_SPEC), out, ws);
  } else {
    kapply<<<dim3(NB * NC), dim3(256), 0, stream>>>(x, out, ws);
  }
}